// Round 1
// baseline (453.104 us; speedup 1.0000x reference)
//
#include <hip/hip_runtime.h>
#include <hip/hip_bf16.h>
#include <cstdint>

typedef __bf16 bf16;
typedef bf16 bf16x4 __attribute__((ext_vector_type(4)));
typedef bf16 bf16x8 __attribute__((ext_vector_type(8)));
typedef float f32x4 __attribute__((ext_vector_type(4)));

#define MFMA16(a, b, c) __builtin_amdgcn_mfma_f32_16x16x32_bf16((a), (b), (c), 0, 0, 0)

// ------------------------------------------------------------------
// cast fp32 -> bf16, 4 elems/thread
// ------------------------------------------------------------------
__global__ void cast_f32_to_bf16(const float* __restrict__ src,
                                 bf16* __restrict__ dst, int n4) {
  int i = blockIdx.x * blockDim.x + threadIdx.x;
  if (i < n4) {
    const float4 v = ((const float4*)src)[i];
    bf16x4 o;
    o.x = (bf16)v.x; o.y = (bf16)v.y; o.z = (bf16)v.z; o.w = (bf16)v.w;
    ((bf16x4*)dst)[i] = o;
  }
}

// ------------------------------------------------------------------
// GEMM1: C[m,e] = sum_c x[m,c] * W1[e,c]   (M=8192, N=1536, K=1024)
// epilogue scatters to q[B,H,T,D], k[B,KVH,T,D], v[B,KVH,T,D] (bf16)
// Block: 256 thr = 4 waves, tile 128x128, BK=64. LDS stride 72 (pad).
// ------------------------------------------------------------------
__global__ __launch_bounds__(256, 2)
void gemm_qkv(const bf16* __restrict__ A, const bf16* __restrict__ B,
              bf16* __restrict__ qb, bf16* __restrict__ kb, bf16* __restrict__ vb) {
  constexpr int K = 1024;
  __shared__ bf16 sA[128 * 72];
  __shared__ bf16 sB[128 * 72];
  const int tid = threadIdx.x;
  const int lane = tid & 63, wid = tid >> 6;
  const int col = lane & 15, quad = lane >> 4;
  const int wm = wid >> 1, wn = wid & 1;
  const int m0 = blockIdx.y * 128, n0 = blockIdx.x * 128;

  f32x4 acc[4][4];
  const f32x4 z = {0.f, 0.f, 0.f, 0.f};
#pragma unroll
  for (int mi = 0; mi < 4; mi++)
#pragma unroll
    for (int ni = 0; ni < 4; ni++) acc[mi][ni] = z;

  for (int k0 = 0; k0 < K; k0 += 64) {
    __syncthreads();
#pragma unroll
    for (int c = 0; c < 4; ++c) {
      int idx = c * 256 + tid;
      int row = idx >> 3, kc = idx & 7;
      *(bf16x8*)&sA[row * 72 + kc * 8] =
          *(const bf16x8*)&A[(size_t)(m0 + row) * K + k0 + kc * 8];
      *(bf16x8*)&sB[row * 72 + kc * 8] =
          *(const bf16x8*)&B[(size_t)(n0 + row) * K + k0 + kc * 8];
    }
    __syncthreads();
#pragma unroll
    for (int ks = 0; ks < 2; ++ks) {
      const int kk = ks * 32 + quad * 8;
      bf16x8 af[4], bfr[4];
#pragma unroll
      for (int i = 0; i < 4; i++)
        af[i] = *(const bf16x8*)&sA[(wm * 64 + i * 16 + col) * 72 + kk];
#pragma unroll
      for (int i = 0; i < 4; i++)
        bfr[i] = *(const bf16x8*)&sB[(wn * 64 + i * 16 + col) * 72 + kk];
#pragma unroll
      for (int mi = 0; mi < 4; mi++)
#pragma unroll
        for (int ni = 0; ni < 4; ni++)
          acc[mi][ni] = MFMA16(af[mi], bfr[ni], acc[mi][ni]);
    }
  }
  // epilogue: scatter into q/k/v layouts
#pragma unroll
  for (int mi = 0; mi < 4; mi++) {
#pragma unroll
    for (int ni = 0; ni < 4; ni++) {
      const int e = n0 + wn * 64 + ni * 16 + col;
#pragma unroll
      for (int r = 0; r < 4; r++) {
        const int m = m0 + wm * 64 + mi * 16 + quad * 4 + r;
        const int bb = m >> 11, t = m & 2047;
        const bf16 val = (bf16)acc[mi][ni][r];
        if (e < 1024) {
          qb[(((size_t)bb * 16 + (e >> 6)) * 2048 + t) * 64 + (e & 63)] = val;
        } else if (e < 1280) {
          const int f = e - 1024;
          kb[(((size_t)bb * 4 + (f >> 6)) * 2048 + t) * 64 + (f & 63)] = val;
        } else {
          const int f = e - 1280;
          vb[(((size_t)bb * 4 + (f >> 6)) * 2048 + t) * 64 + (f & 63)] = val;
        }
      }
    }
  }
}

// ------------------------------------------------------------------
// GEMM2: out[m,e] = sum_c AO[m,c] * Wproj[e,c] + bias[e]  (fp32 out)
// ------------------------------------------------------------------
__global__ __launch_bounds__(256, 2)
void gemm_proj(const bf16* __restrict__ A, const bf16* __restrict__ B,
               const float* __restrict__ bias, float* __restrict__ out) {
  constexpr int K = 1024;
  __shared__ bf16 sA[128 * 72];
  __shared__ bf16 sB[128 * 72];
  const int tid = threadIdx.x;
  const int lane = tid & 63, wid = tid >> 6;
  const int col = lane & 15, quad = lane >> 4;
  const int wm = wid >> 1, wn = wid & 1;
  const int m0 = blockIdx.y * 128, n0 = blockIdx.x * 128;

  f32x4 acc[4][4];
  const f32x4 z = {0.f, 0.f, 0.f, 0.f};
#pragma unroll
  for (int mi = 0; mi < 4; mi++)
#pragma unroll
    for (int ni = 0; ni < 4; ni++) acc[mi][ni] = z;

  for (int k0 = 0; k0 < K; k0 += 64) {
    __syncthreads();
#pragma unroll
    for (int c = 0; c < 4; ++c) {
      int idx = c * 256 + tid;
      int row = idx >> 3, kc = idx & 7;
      *(bf16x8*)&sA[row * 72 + kc * 8] =
          *(const bf16x8*)&A[(size_t)(m0 + row) * K + k0 + kc * 8];
      *(bf16x8*)&sB[row * 72 + kc * 8] =
          *(const bf16x8*)&B[(size_t)(n0 + row) * K + k0 + kc * 8];
    }
    __syncthreads();
#pragma unroll
    for (int ks = 0; ks < 2; ++ks) {
      const int kk = ks * 32 + quad * 8;
      bf16x8 af[4], bfr[4];
#pragma unroll
      for (int i = 0; i < 4; i++)
        af[i] = *(const bf16x8*)&sA[(wm * 64 + i * 16 + col) * 72 + kk];
#pragma unroll
      for (int i = 0; i < 4; i++)
        bfr[i] = *(const bf16x8*)&sB[(wn * 64 + i * 16 + col) * 72 + kk];
#pragma unroll
      for (int mi = 0; mi < 4; mi++)
#pragma unroll
        for (int ni = 0; ni < 4; ni++)
          acc[mi][ni] = MFMA16(af[mi], bfr[ni], acc[mi][ni]);
    }
  }
#pragma unroll
  for (int mi = 0; mi < 4; mi++) {
#pragma unroll
    for (int ni = 0; ni < 4; ni++) {
      const int e = n0 + wn * 64 + ni * 16 + col;
      const float be = bias[e];
#pragma unroll
      for (int r = 0; r < 4; r++) {
        const int m = m0 + wm * 64 + mi * 16 + quad * 4 + r;
        out[(size_t)m * 1024 + e] = acc[mi][ni][r] + be;
      }
    }
  }
}

// ------------------------------------------------------------------
// Flash attention with ALiBi bias (no causal mask: bias=0 above diag).
// Block: 4 waves x 64 q rows = 256 q rows. KV chunk 64.
// scores[i,j] = 0.125*(q.k) + (j<=i ? 0.125*slope_h*(j-i) : 0)
// ------------------------------------------------------------------
__global__ __launch_bounds__(256, 2)
void attn_alibi(const bf16* __restrict__ qb, const bf16* __restrict__ kb,
                const bf16* __restrict__ vb, bf16* __restrict__ ob) {
  __shared__ bf16 sK[64 * 72];     // [kv][d]
  __shared__ bf16 sV[64 * 72];     // transposed: [d][kv]
  __shared__ bf16 sP[4][64 * 72];  // per wave: [q][kv]
  const int tid = threadIdx.x;
  const int lane = tid & 63, wid = tid >> 6;
  const int col = lane & 15, quad = lane >> 4;
  const int bh = blockIdx.y;
  const int b = bh >> 4, h = bh & 15, kvh = h & 3;
  const int qbase = blockIdx.x * 256 + wid * 64;

  const bf16* qptr = qb + ((size_t)(b * 16 + h) * 2048 + qbase) * 64;
  const bf16* kptr = kb + ((size_t)(b * 4 + kvh) * 2048) * 64;
  const bf16* vptr = vb + ((size_t)(b * 4 + kvh) * 2048) * 64;

  // Q resident in registers, A-operand layout: A[m=lane&15][k=quad*8+j]
  bf16x8 aq[4][2];
#pragma unroll
  for (int mi = 0; mi < 4; mi++)
#pragma unroll
    for (int ks = 0; ks < 2; ks++)
      aq[mi][ks] = *(const bf16x8*)&qptr[(mi * 16 + col) * 64 + ks * 32 + quad * 8];

  f32x4 O[4][4];
  const f32x4 z = {0.f, 0.f, 0.f, 0.f};
#pragma unroll
  for (int mi = 0; mi < 4; mi++)
#pragma unroll
    for (int nd = 0; nd < 4; nd++) O[mi][nd] = z;
  float mrow[4][4], lrow[4][4];
#pragma unroll
  for (int mi = 0; mi < 4; mi++)
#pragma unroll
    for (int r = 0; r < 4; r++) { mrow[mi][r] = -1e30f; lrow[mi][r] = 0.f; }

  const float slope8 = exp2f(-0.5f * (float)(h + 1)) * 0.125f;

  for (int c0 = 0; c0 < 2048; c0 += 64) {
    __syncthreads();  // protect sK/sV/sP reads of previous chunk
    // stage K [64 kv][64 d] -> sK (padded 72)
#pragma unroll
    for (int c = 0; c < 2; c++) {
      int idx = c * 256 + tid, row = idx >> 3, kc = idx & 7;
      *(bf16x8*)&sK[row * 72 + kc * 8] =
          *(const bf16x8*)&kptr[(size_t)(c0 + row) * 64 + kc * 8];
    }
    // stage V transposed: sV[d][kv]
#pragma unroll
    for (int c = 0; c < 2; c++) {
      int idx = c * 256 + tid, row = idx >> 3, dc = idx & 7;
      bf16x8 v = *(const bf16x8*)&vptr[(size_t)(c0 + row) * 64 + dc * 8];
#pragma unroll
      for (int j = 0; j < 8; j++) sV[(dc * 8 + j) * 72 + row] = v[j];
    }
    __syncthreads();

    // S = Q @ K^T  (64 q x 64 kv per wave)
    f32x4 S[4][4];
#pragma unroll
    for (int mi = 0; mi < 4; mi++)
#pragma unroll
      for (int ni = 0; ni < 4; ni++) S[mi][ni] = z;
#pragma unroll
    for (int ks = 0; ks < 2; ks++) {
      const int kk = ks * 32 + quad * 8;
      bf16x8 bk[4];
#pragma unroll
      for (int ni = 0; ni < 4; ni++)
        bk[ni] = *(const bf16x8*)&sK[(ni * 16 + col) * 72 + kk];
#pragma unroll
      for (int mi = 0; mi < 4; mi++)
#pragma unroll
        for (int ni = 0; ni < 4; ni++)
          S[mi][ni] = MFMA16(aq[mi][ks], bk[ni], S[mi][ni]);
    }

    // bias + online softmax. C-layout: row = quad*4+r, col = lane&15
#pragma unroll
    for (int mi = 0; mi < 4; mi++) {
#pragma unroll
      for (int r = 0; r < 4; r++) {
        const int gi = qbase + mi * 16 + quad * 4 + r;
#pragma unroll
        for (int ni = 0; ni < 4; ni++) {
          const int gj = c0 + ni * 16 + col;
          float sv = S[mi][ni][r] * 0.125f;
          if (gj <= gi) sv += slope8 * (float)(gj - gi);
          S[mi][ni][r] = sv;
        }
        float cm = fmaxf(fmaxf(S[mi][0][r], S[mi][1][r]),
                         fmaxf(S[mi][2][r], S[mi][3][r]));
        cm = fmaxf(cm, __shfl_xor(cm, 1));
        cm = fmaxf(cm, __shfl_xor(cm, 2));
        cm = fmaxf(cm, __shfl_xor(cm, 4));
        cm = fmaxf(cm, __shfl_xor(cm, 8));
        const float mold = mrow[mi][r];
        const float mn = fmaxf(mold, cm);
        const float alpha = __expf(mold - mn);
        float ps = 0.f;
#pragma unroll
        for (int ni = 0; ni < 4; ni++) {
          const float p = __expf(S[mi][ni][r] - mn);
          S[mi][ni][r] = p;
          ps += p;
        }
        ps += __shfl_xor(ps, 1);
        ps += __shfl_xor(ps, 2);
        ps += __shfl_xor(ps, 4);
        ps += __shfl_xor(ps, 8);
        lrow[mi][r] = lrow[mi][r] * alpha + ps;
        mrow[mi][r] = mn;
#pragma unroll
        for (int nd = 0; nd < 4; nd++) O[mi][nd][r] *= alpha;
        const int prow = mi * 16 + quad * 4 + r;
#pragma unroll
        for (int ni = 0; ni < 4; ni++)
          sP[wid][prow * 72 + ni * 16 + col] = (bf16)S[mi][ni][r];
      }
    }
    __syncthreads();  // P LDS visible (also covers cross-wave K/V read完)

    // O += P @ V  (P: A-layout from sP; V: B-layout from sV[d][kv])
#pragma unroll
    for (int ks = 0; ks < 2; ks++) {
      const int kk = ks * 32 + quad * 8;
      bf16x8 ap[4], bv[4];
#pragma unroll
      for (int mi = 0; mi < 4; mi++)
        ap[mi] = *(const bf16x8*)&sP[wid][(mi * 16 + col) * 72 + kk];
#pragma unroll
      for (int nd = 0; nd < 4; nd++)
        bv[nd] = *(const bf16x8*)&sV[(nd * 16 + col) * 72 + kk];
#pragma unroll
      for (int mi = 0; mi < 4; mi++)
#pragma unroll
        for (int nd = 0; nd < 4; nd++)
          O[mi][nd] = MFMA16(ap[mi], bv[nd], O[mi][nd]);
    }
  }

  // epilogue: ob[b, t, h*64 + d] bf16
#pragma unroll
  for (int mi = 0; mi < 4; mi++) {
#pragma unroll
    for (int r = 0; r < 4; r++) {
      const float inv = 1.f / lrow[mi][r];
      const int t = qbase + mi * 16 + quad * 4 + r;
#pragma unroll
      for (int nd = 0; nd < 4; nd++) {
        ob[((size_t)b * 2048 + t) * 1024 + h * 64 + nd * 16 + col] =
            (bf16)(O[mi][nd][r] * inv);
      }
    }
  }
}

// ------------------------------------------------------------------
extern "C" void kernel_launch(void* const* d_in, const int* in_sizes, int n_in,
                              void* d_out, int out_size, void* d_ws, size_t ws_size,
                              hipStream_t stream) {
  const float* x     = (const float*)d_in[0];
  const float* Wq    = (const float*)d_in[1];
  const float* Wkv   = (const float*)d_in[2];
  const float* Wproj = (const float*)d_in[3];
  const float* bproj = (const float*)d_in[4];
  float* out = (float*)d_out;

  // workspace layout (bf16 elements)
  bf16* xb  = (bf16*)d_ws;            // 8192*1024
  bf16* w1b = xb  + 8388608;          // 1536*1024 (Wq rows then Wkv rows)
  bf16* wpb = w1b + 1572864;          // 1024*1024
  bf16* qb  = wpb + 1048576;          // [4,16,2048,64]
  bf16* kb  = qb  + 8388608;          // [4,4,2048,64]
  bf16* vb  = kb  + 2097152;          // [4,4,2048,64]
  bf16* aob = vb  + 2097152;          // [4,2048,1024]

  cast_f32_to_bf16<<<8192, 256, 0, stream>>>(x, xb, 2097152);
  cast_f32_to_bf16<<<1024, 256, 0, stream>>>(Wq, w1b, 262144);
  cast_f32_to_bf16<<<512, 256, 0, stream>>>(Wkv, w1b + 1048576, 131072);
  cast_f32_to_bf16<<<1024, 256, 0, stream>>>(Wproj, wpb, 262144);

  gemm_qkv<<<dim3(12, 64), 256, 0, stream>>>(xb, w1b, qb, kb, vb);
  attn_alibi<<<dim3(8, 64), 256, 0, stream>>>(qb, kb, vb, aob);
  gemm_proj<<<dim3(8, 64), 256, 0, stream>>>(aob, wpb, bproj, out);
}

// Round 2
// 276.858 us; speedup vs baseline: 1.6366x; 1.6366x over previous
//
#include <hip/hip_runtime.h>
#include <hip/hip_bf16.h>
#include <cstdint>

typedef __bf16 bf16;
typedef bf16 bf16x4 __attribute__((ext_vector_type(4)));
typedef bf16 bf16x8 __attribute__((ext_vector_type(8)));
typedef float f32x4 __attribute__((ext_vector_type(4)));

#define MFMA16(a, b, c) __builtin_amdgcn_mfma_f32_16x16x32_bf16((a), (b), (c), 0, 0, 0)

// ------------------------------------------------------------------
// cast fp32 -> bf16, 4 elems/thread
// ------------------------------------------------------------------
__global__ void cast_f32_to_bf16(const float* __restrict__ src,
                                 bf16* __restrict__ dst, int n4) {
  int i = blockIdx.x * blockDim.x + threadIdx.x;
  if (i < n4) {
    const float4 v = ((const float4*)src)[i];
    bf16x4 o;
    o.x = (bf16)v.x; o.y = (bf16)v.y; o.z = (bf16)v.z; o.w = (bf16)v.w;
    ((bf16x4*)dst)[i] = o;
  }
}

// ------------------------------------------------------------------
// GEMM1: C[m,e] = sum_c x[m,c] * W1[e,c]   (M=8192, N=1536, K=1024)
// ------------------------------------------------------------------
__global__ __launch_bounds__(256, 2)
void gemm_qkv(const bf16* __restrict__ A, const bf16* __restrict__ B,
              bf16* __restrict__ qb, bf16* __restrict__ kb, bf16* __restrict__ vb) {
  constexpr int K = 1024;
  __shared__ bf16 sA[128 * 72];
  __shared__ bf16 sB[128 * 72];
  const int tid = threadIdx.x;
  const int lane = tid & 63, wid = tid >> 6;
  const int col = lane & 15, quad = lane >> 4;
  const int wm = wid >> 1, wn = wid & 1;
  const int m0 = blockIdx.y * 128, n0 = blockIdx.x * 128;

  f32x4 acc[4][4];
  const f32x4 z = {0.f, 0.f, 0.f, 0.f};
#pragma unroll
  for (int mi = 0; mi < 4; mi++)
#pragma unroll
    for (int ni = 0; ni < 4; ni++) acc[mi][ni] = z;

  for (int k0 = 0; k0 < K; k0 += 64) {
    __syncthreads();
#pragma unroll
    for (int c = 0; c < 4; ++c) {
      int idx = c * 256 + tid;
      int row = idx >> 3, kc = idx & 7;
      *(bf16x8*)&sA[row * 72 + kc * 8] =
          *(const bf16x8*)&A[(size_t)(m0 + row) * K + k0 + kc * 8];
      *(bf16x8*)&sB[row * 72 + kc * 8] =
          *(const bf16x8*)&B[(size_t)(n0 + row) * K + k0 + kc * 8];
    }
    __syncthreads();
#pragma unroll
    for (int ks = 0; ks < 2; ++ks) {
      const int kk = ks * 32 + quad * 8;
      bf16x8 af[4], bfr[4];
#pragma unroll
      for (int i = 0; i < 4; i++)
        af[i] = *(const bf16x8*)&sA[(wm * 64 + i * 16 + col) * 72 + kk];
#pragma unroll
      for (int i = 0; i < 4; i++)
        bfr[i] = *(const bf16x8*)&sB[(wn * 64 + i * 16 + col) * 72 + kk];
#pragma unroll
      for (int mi = 0; mi < 4; mi++)
#pragma unroll
        for (int ni = 0; ni < 4; ni++)
          acc[mi][ni] = MFMA16(af[mi], bfr[ni], acc[mi][ni]);
    }
  }
#pragma unroll
  for (int mi = 0; mi < 4; mi++) {
#pragma unroll
    for (int ni = 0; ni < 4; ni++) {
      const int e = n0 + wn * 64 + ni * 16 + col;
#pragma unroll
      for (int r = 0; r < 4; r++) {
        const int m = m0 + wm * 64 + mi * 16 + quad * 4 + r;
        const int bb = m >> 11, t = m & 2047;
        const bf16 val = (bf16)acc[mi][ni][r];
        if (e < 1024) {
          qb[(((size_t)bb * 16 + (e >> 6)) * 2048 + t) * 64 + (e & 63)] = val;
        } else if (e < 1280) {
          const int f = e - 1024;
          kb[(((size_t)bb * 4 + (f >> 6)) * 2048 + t) * 64 + (f & 63)] = val;
        } else {
          const int f = e - 1280;
          vb[(((size_t)bb * 4 + (f >> 6)) * 2048 + t) * 64 + (f & 63)] = val;
        }
      }
    }
  }
}

// ------------------------------------------------------------------
// GEMM2: out[m,e] = sum_c AO[m,c] * Wproj[e,c] + bias[e]  (fp32 out)
// ------------------------------------------------------------------
__global__ __launch_bounds__(256, 2)
void gemm_proj(const bf16* __restrict__ A, const bf16* __restrict__ B,
               const float* __restrict__ bias, float* __restrict__ out) {
  constexpr int K = 1024;
  __shared__ bf16 sA[128 * 72];
  __shared__ bf16 sB[128 * 72];
  const int tid = threadIdx.x;
  const int lane = tid & 63, wid = tid >> 6;
  const int col = lane & 15, quad = lane >> 4;
  const int wm = wid >> 1, wn = wid & 1;
  const int m0 = blockIdx.y * 128, n0 = blockIdx.x * 128;

  f32x4 acc[4][4];
  const f32x4 z = {0.f, 0.f, 0.f, 0.f};
#pragma unroll
  for (int mi = 0; mi < 4; mi++)
#pragma unroll
    for (int ni = 0; ni < 4; ni++) acc[mi][ni] = z;

  for (int k0 = 0; k0 < K; k0 += 64) {
    __syncthreads();
#pragma unroll
    for (int c = 0; c < 4; ++c) {
      int idx = c * 256 + tid;
      int row = idx >> 3, kc = idx & 7;
      *(bf16x8*)&sA[row * 72 + kc * 8] =
          *(const bf16x8*)&A[(size_t)(m0 + row) * K + k0 + kc * 8];
      *(bf16x8*)&sB[row * 72 + kc * 8] =
          *(const bf16x8*)&B[(size_t)(n0 + row) * K + k0 + kc * 8];
    }
    __syncthreads();
#pragma unroll
    for (int ks = 0; ks < 2; ++ks) {
      const int kk = ks * 32 + quad * 8;
      bf16x8 af[4], bfr[4];
#pragma unroll
      for (int i = 0; i < 4; i++)
        af[i] = *(const bf16x8*)&sA[(wm * 64 + i * 16 + col) * 72 + kk];
#pragma unroll
      for (int i = 0; i < 4; i++)
        bfr[i] = *(const bf16x8*)&sB[(wn * 64 + i * 16 + col) * 72 + kk];
#pragma unroll
      for (int mi = 0; mi < 4; mi++)
#pragma unroll
        for (int ni = 0; ni < 4; ni++)
          acc[mi][ni] = MFMA16(af[mi], bfr[ni], acc[mi][ni]);
    }
  }
#pragma unroll
  for (int mi = 0; mi < 4; mi++) {
#pragma unroll
    for (int ni = 0; ni < 4; ni++) {
      const int e = n0 + wn * 64 + ni * 16 + col;
      const float be = bias[e];
#pragma unroll
      for (int r = 0; r < 4; r++) {
        const int m = m0 + wm * 64 + mi * 16 + quad * 4 + r;
        out[(size_t)m * 1024 + e] = acc[mi][ni][r] + be;
      }
    }
  }
}

// ------------------------------------------------------------------
// Flash attention, ALiBi bias (no causal mask), FIXED-max softmax.
// Transposed dataflow: S^T = K Q^T so softmax state is per-column
// (in-lane sums, no shuffles in the loop).  P round-trips LDS with
// vectorized b64 writes; V staged transposed with xor-block swizzle.
// Block: 4 waves x 64 q rows. KV chunk 64.
// ------------------------------------------------------------------
__global__ __launch_bounds__(256, 2)
void attn_alibi(const bf16* __restrict__ qb, const bf16* __restrict__ kb,
                const bf16* __restrict__ vb, bf16* __restrict__ ob) {
  __shared__ bf16 sK[64 * 72];      // [kv][d], stride 72
  __shared__ bf16 sVt[64 * 72];     // [d][kv], kv-block xor-swizzled by d>>3
  __shared__ bf16 sPt[4][64 * 72];  // per wave: [q][kv]
  __shared__ float sL[4][64];       // per wave: row sums for transpose
  const int tid = threadIdx.x;
  const int lane = tid & 63, wid = tid >> 6;
  const int col = lane & 15, quad = lane >> 4;
  const int bh = blockIdx.y;
  const int b = bh >> 4, h = bh & 15, kvh = h & 3;
  const int qbase = __builtin_amdgcn_readfirstlane(blockIdx.x * 256 + wid * 64);

  const bf16* qptr = qb + ((size_t)(b * 16 + h) * 2048 + qbase) * 64;
  const bf16* kptr = kb + ((size_t)(b * 4 + kvh) * 2048) * 64;
  const bf16* vptr = vb + ((size_t)(b * 4 + kvh) * 2048) * 64;

  // Q resident as B-operand frags: B[n=q (col)][k=d=ks*32+quad*8+j]
  bf16x8 bq[4][2];
#pragma unroll
  for (int ni = 0; ni < 4; ni++)
#pragma unroll
    for (int ks = 0; ks < 2; ks++)
      bq[ni][ks] = *(const bf16x8*)&qptr[(ni * 16 + col) * 64 + ks * 32 + quad * 8];

  f32x4 O[4][4];  // O[q-tile][d-tile], C-layout rows=q
  const f32x4 z = {0.f, 0.f, 0.f, 0.f};
#pragma unroll
  for (int mi = 0; mi < 4; mi++)
#pragma unroll
    for (int nd = 0; nd < 4; nd++) O[mi][nd] = z;
  float lsum[4] = {0.f, 0.f, 0.f, 0.f};

  // exp2-domain constants: p = exp2(qk*c1 + rel*cb), rel<=0 only
  const float c1 = 0.125f * 1.44269504f;
  const float cb = exp2f(-0.5f * (float)(h + 1)) * c1;
  const int qoff = quad * 4 - col;  // rel = U + qoff + r

  for (int c0 = 0; c0 < 2048; c0 += 64) {
    __syncthreads();
    // stage K: [kv][d] rows, b128
#pragma unroll
    for (int c = 0; c < 2; c++) {
      int idx = c * 256 + tid, row = idx >> 3, kc = idx & 7;
      *(bf16x8*)&sK[row * 72 + kc * 8] =
          *(const bf16x8*)&kptr[(size_t)(c0 + row) * 64 + kc * 8];
    }
    // stage V transposed + swizzled: elem (kv,d) at d*72 + ((kv>>3)^(d>>3))*8 + (kv&7)
#pragma unroll
    for (int c = 0; c < 2; c++) {
      int idx = c * 256 + tid, row = idx >> 3, dc = idx & 7;
      bf16x8 v = *(const bf16x8*)&vptr[(size_t)(c0 + row) * 64 + dc * 8];
      const int blk = row >> 3, rl = row & 7;
#pragma unroll
      for (int j = 0; j < 8; j++)
        sVt[(dc * 8 + j) * 72 + ((blk ^ dc) << 3) + rl] = v[j];
    }
    __syncthreads();

    // S^T = K Q^T : rows=kv, cols=q
    f32x4 S[4][4];
#pragma unroll
    for (int mi = 0; mi < 4; mi++)
#pragma unroll
      for (int ni = 0; ni < 4; ni++) S[mi][ni] = z;
#pragma unroll
    for (int ks = 0; ks < 2; ks++) {
      bf16x8 ak[4];
#pragma unroll
      for (int mi = 0; mi < 4; mi++)
        ak[mi] = *(const bf16x8*)&sK[(mi * 16 + col) * 72 + ks * 32 + quad * 8];
#pragma unroll
      for (int mi = 0; mi < 4; mi++)
#pragma unroll
        for (int ni = 0; ni < 4; ni++)
          S[mi][ni] = MFMA16(ak[mi], bq[ni][ks], S[mi][ni]);
    }

    // bias + exp2 (fixed max M=0), in-lane partial row sums, pack P
    bf16* sp = sPt[wid];
#pragma unroll
    for (int ni = 0; ni < 4; ni++) {
      f32x4 p[4];
#pragma unroll
      for (int mi = 0; mi < 4; mi++) {
        const int U = c0 + mi * 16 - qbase - ni * 16;  // wave-uniform
        if (U <= -15) {
          const float bb = cb * (float)(U + qoff);
#pragma unroll
          for (int r = 0; r < 4; r++)
            p[mi][r] = __builtin_amdgcn_exp2f(S[mi][ni][r] * c1 + (bb + cb * (float)r));
        } else if (U >= 16) {
#pragma unroll
          for (int r = 0; r < 4; r++)
            p[mi][r] = __builtin_amdgcn_exp2f(S[mi][ni][r] * c1);
        } else {
          const float relf = (float)(U + qoff);
#pragma unroll
          for (int r = 0; r < 4; r++) {
            const float rr = relf + (float)r;
            const float bb = (rr <= 0.f) ? cb * rr : 0.f;
            p[mi][r] = __builtin_amdgcn_exp2f(S[mi][ni][r] * c1 + bb);
          }
        }
      }
      f32x4 t = (p[0] + p[1]) + (p[2] + p[3]);
      lsum[ni] += (t.x + t.y) + (t.z + t.w);
#pragma unroll
      for (int mi = 0; mi < 4; mi++) {
        bf16x4 w;
#pragma unroll
        for (int r = 0; r < 4; r++) w[r] = (bf16)p[mi][r];
        *(bf16x4*)&sp[(ni * 16 + col) * 72 + mi * 16 + quad * 4] = w;
      }
    }

    // O += P V : A = P rows (sPt), B = V^T rows (sVt, swizzled)
#pragma unroll
    for (int ks = 0; ks < 2; ks++) {
      bf16x8 ap[4], bv[4];
#pragma unroll
      for (int mi = 0; mi < 4; mi++)
        ap[mi] = *(const bf16x8*)&sp[(mi * 16 + col) * 72 + ks * 32 + quad * 8];
#pragma unroll
      for (int nd = 0; nd < 4; nd++) {
        const int d = nd * 16 + col;
        bv[nd] = *(const bf16x8*)&sVt[d * 72 + (((ks * 4 + quad) ^ (d >> 3)) << 3)];
      }
#pragma unroll
      for (int mi = 0; mi < 4; mi++)
#pragma unroll
        for (int nd = 0; nd < 4; nd++)
          O[mi][nd] = MFMA16(ap[mi], bv[nd], O[mi][nd]);
    }
  }

  // finish row sums: cross-quad reduce, then transpose via LDS
#pragma unroll
  for (int ni = 0; ni < 4; ni++) {
    float l = lsum[ni];
    l += __shfl_xor(l, 16);
    l += __shfl_xor(l, 32);
    lsum[ni] = l;
  }
  __syncthreads();
  if (quad == 0) {
#pragma unroll
    for (int ni = 0; ni < 4; ni++) sL[wid][ni * 16 + col] = lsum[ni];
  }
  __syncthreads();

  // epilogue: ob[b, t, h*64 + d] = O * (1/l)
#pragma unroll
  for (int mi = 0; mi < 4; mi++) {
    const f32x4 lv = *(const f32x4*)&sL[wid][mi * 16 + quad * 4];
#pragma unroll
    for (int r = 0; r < 4; r++) {
      const float inv = 1.0f / lv[r];
      const int t = qbase + mi * 16 + quad * 4 + r;
#pragma unroll
      for (int nd = 0; nd < 4; nd++) {
        ob[((size_t)b * 2048 + t) * 1024 + h * 64 + nd * 16 + col] =
            (bf16)(O[mi][nd][r] * inv);
      }
    }
  }
}

// ------------------------------------------------------------------
extern "C" void kernel_launch(void* const* d_in, const int* in_sizes, int n_in,
                              void* d_out, int out_size, void* d_ws, size_t ws_size,
                              hipStream_t stream) {
  const float* x     = (const float*)d_in[0];
  const float* Wq    = (const float*)d_in[1];
  const float* Wkv   = (const float*)d_in[2];
  const float* Wproj = (const float*)d_in[3];
  const float* bproj = (const float*)d_in[4];
  float* out = (float*)d_out;

  // workspace layout (bf16 elements)
  bf16* xb  = (bf16*)d_ws;            // 8192*1024
  bf16* w1b = xb  + 8388608;          // 1536*1024 (Wq rows then Wkv rows)
  bf16* wpb = w1b + 1572864;          // 1024*1024
  bf16* qb  = wpb + 1048576;          // [4,16,2048,64]
  bf16* kb  = qb  + 8388608;          // [4,4,2048,64]
  bf16* vb  = kb  + 2097152;          // [4,4,2048,64]
  bf16* aob = vb  + 2097152;          // [4,2048,1024]

  cast_f32_to_bf16<<<8192, 256, 0, stream>>>(x, xb, 2097152);
  cast_f32_to_bf16<<<1024, 256, 0, stream>>>(Wq, w1b, 262144);
  cast_f32_to_bf16<<<512, 256, 0, stream>>>(Wkv, w1b + 1048576, 131072);
  cast_f32_to_bf16<<<1024, 256, 0, stream>>>(Wproj, wpb, 262144);

  gemm_qkv<<<dim3(12, 64), 256, 0, stream>>>(xb, w1b, qb, kb, vb);
  attn_alibi<<<dim3(8, 64), 256, 0, stream>>>(qb, kb, vb, aob);
  gemm_proj<<<dim3(8, 64), 256, 0, stream>>>(aob, wpb, bproj, out);
}